// Round 1
// baseline (14535.066 us; speedup 1.0000x reference)
//
#include <hip/hip_runtime.h>

// Problem constants (validated at runtime from in_sizes)
#define IN_DIM 128

__device__ __forceinline__ float lrelu(float x) { return x > 0.f ? x : 0.2f * x; }

// Order-preserving float -> uint encoding for atomicMax (init with 0x00000000;
// any real float encodes > 0, and every dst has a self-loop so the sentinel is
// always overwritten before decode).
__device__ __forceinline__ unsigned enc_f(float x) {
    unsigned b = __float_as_uint(x);
    return (b & 0x80000000u) ? ~b : (b | 0x80000000u);
}
__device__ __forceinline__ float dec_f(unsigned e) {
    unsigned b = (e & 0x80000000u) ? (e & 0x7fffffffu) : ~e;
    return __uint_as_float(b);
}

// h[n, HC] = in[n, F] @ W[F, HC]
template<int F, int HC>
__global__ __launch_bounds__(256) void gemm_kernel(const float* __restrict__ in,
                                                   const float* __restrict__ W,
                                                   float* __restrict__ h, int n) {
    constexpr int NPB = 256 / HC;  // nodes per block
    __shared__ float wl[F * HC];
    __shared__ float xl[NPB * F];
    const int t = threadIdx.x;
    for (int i = t; i < F * HC; i += 256) wl[i] = W[i];
    const int node0 = blockIdx.x * NPB;
    for (int i = t; i < NPB * F; i += 256) {
        int node = node0 + i / F;
        xl[i] = (node < n) ? in[node * F + (i % F)] : 0.f;
    }
    __syncthreads();
    const int nl = t / HC, col = t % HC;
    const int node = node0 + nl;
    if (node >= n) return;
    float acc = 0.f;
#pragma unroll
    for (int k = 0; k < F; ++k) acc += xl[nl * F + k] * wl[k * HC + col];
    h[node * HC + col] = acc;
}

// al_s[n,h] = sum_c h[n,h,c] * a_s[h,c]; same for al_d
template<int H, int C>
__global__ __launch_bounds__(256) void al_kernel(const float* __restrict__ h,
                                                 const float* __restrict__ a_s,
                                                 const float* __restrict__ a_d,
                                                 float* __restrict__ als,
                                                 float* __restrict__ ald, int n) {
    int tid = blockIdx.x * blockDim.x + threadIdx.x;
    if (tid >= n * H) return;
    int node = tid / H, hh = tid % H;
    const float* hp = h + (node * H + hh) * C;
    const float* as = a_s + hh * C;
    const float* ad = a_d + hh * C;
    float s = 0.f, d0 = 0.f;
#pragma unroll
    for (int c = 0; c < C; ++c) {
        float v = hp[c];
        s += v * as[c];
        d0 += v * ad[c];
    }
    als[tid] = s;
    ald[tid] = d0;
}

// Segment max of edge logits into menc[dst,h] (encoded uint atomicMax).
template<int H>
__global__ __launch_bounds__(256) void edge_max_kernel(const int* __restrict__ ei,
                                                       const float* __restrict__ als,
                                                       const float* __restrict__ ald,
                                                       unsigned* __restrict__ menc,
                                                       int ne, int n) {
    int e = blockIdx.x * blockDim.x + threadIdx.x;
    if (e >= ne + n) return;
    int s, d;
    if (e < ne) { s = ei[e]; d = ei[ne + e]; } else { s = d = e - ne; }
#pragma unroll
    for (int hh = 0; hh < H; ++hh) {
        float ev = lrelu(als[s * H + hh] + ald[d * H + hh]);
        atomicMax(menc + d * H + hh, enc_f(ev));
    }
}

// For each (edge, head): w = exp(e - m[dst]); denom[dst,h] += w;
// acc[dst,h,:] += w * hfeat[src,h,:]
template<int H, int C>
__global__ __launch_bounds__(256) void edge_acc_kernel(const int* __restrict__ ei,
                                                       const float* __restrict__ als,
                                                       const float* __restrict__ ald,
                                                       const unsigned* __restrict__ menc,
                                                       const float* __restrict__ hfeat,
                                                       float* __restrict__ denom,
                                                       float* __restrict__ acc,
                                                       int ne, int n) {
    int tid = blockIdx.x * blockDim.x + threadIdx.x;
    if (tid >= (ne + n) * H) return;
    int e = tid / H, hh = tid % H;
    int s, d;
    if (e < ne) { s = ei[e]; d = ei[ne + e]; } else { s = d = e - ne; }
    float ev = lrelu(als[s * H + hh] + ald[d * H + hh]);
    float m = dec_f(menc[d * H + hh]);
    float w = __expf(ev - m);
    atomicAdd(denom + d * H + hh, w);
    const float4* hp = (const float4*)(hfeat + (s * H + hh) * C);
    float* ap = acc + (d * H + hh) * C;
#pragma unroll
    for (int i = 0; i < C / 4; ++i) {
        float4 v = hp[i];
        atomicAdd(ap + 4 * i + 0, w * v.x);
        atomicAdd(ap + 4 * i + 1, w * v.y);
        atomicAdd(ap + 4 * i + 2, w * v.z);
        atomicAdd(ap + 4 * i + 3, w * v.w);
    }
}

// out = relu(BN(acc/denom + bias))
template<int H, int C>
__global__ __launch_bounds__(256) void finalize_kernel(const float* __restrict__ acc,
                                                       const float* __restrict__ denom,
                                                       const float* __restrict__ bias,
                                                       const float* __restrict__ g,
                                                       const float* __restrict__ bb,
                                                       const float* __restrict__ mm,
                                                       const float* __restrict__ vv,
                                                       float* __restrict__ feat, int n) {
    int tid = blockIdx.x * blockDim.x + threadIdx.x;
    if (tid >= n * H * C) return;
    int node = tid / (H * C);
    int col = tid % (H * C);
    int hh = col / C;
    float val = acc[tid] / (denom[node * H + hh] + 1e-16f) + bias[col];
    val = (val - mm[col]) * rsqrtf(vv[col] + 1e-5f) * g[col] + bb[col];
    feat[tid] = fmaxf(val, 0.f);
}

// Per-node MLP: 16 -> relu(8) -> 1
__global__ __launch_bounds__(256) void mlp_kernel(const float* __restrict__ feat,
                                                  const float* __restrict__ w1,
                                                  const float* __restrict__ b1,
                                                  const float* __restrict__ w2,
                                                  const float* __restrict__ b2,
                                                  float* __restrict__ out, int n) {
    int tid = blockIdx.x * blockDim.x + threadIdx.x;
    if (tid >= n) return;
    float f[16];
    const float4* fp = (const float4*)(feat + tid * 16);
#pragma unroll
    for (int i = 0; i < 4; ++i) {
        float4 v = fp[i];
        f[4 * i + 0] = v.x; f[4 * i + 1] = v.y; f[4 * i + 2] = v.z; f[4 * i + 3] = v.w;
    }
    float o = b2[0];
#pragma unroll
    for (int j = 0; j < 8; ++j) {
        float hv = b1[j];
#pragma unroll
        for (int i = 0; i < 16; ++i) hv += f[i] * w1[i * 8 + j];
        hv = fmaxf(hv, 0.f);
        o += hv * w2[j];
    }
    out[tid] = o;
}

extern "C" void kernel_launch(void* const* d_in, const int* in_sizes, int n_in,
                              void* d_out, int out_size, void* d_ws, size_t ws_size,
                              hipStream_t stream) {
    const float* x    = (const float*)d_in[0];
    const int*   ei   = (const int*)d_in[1];
    const float* W1   = (const float*)d_in[2];
    const float* As1  = (const float*)d_in[3];
    const float* Ad1  = (const float*)d_in[4];
    const float* b1   = (const float*)d_in[5];
    const float* bn1g = (const float*)d_in[6];
    const float* bn1b = (const float*)d_in[7];
    const float* bn1m = (const float*)d_in[8];
    const float* bn1v = (const float*)d_in[9];
    const float* W2   = (const float*)d_in[10];
    const float* As2  = (const float*)d_in[11];
    const float* Ad2  = (const float*)d_in[12];
    const float* b2   = (const float*)d_in[13];
    const float* bn2g = (const float*)d_in[14];
    const float* bn2b = (const float*)d_in[15];
    const float* bn2m = (const float*)d_in[16];
    const float* bn2v = (const float*)d_in[17];
    const float* W3   = (const float*)d_in[18];
    const float* As3  = (const float*)d_in[19];
    const float* Ad3  = (const float*)d_in[20];
    const float* b3   = (const float*)d_in[21];
    const float* bn3g = (const float*)d_in[22];
    const float* bn3b = (const float*)d_in[23];
    const float* bn3m = (const float*)d_in[24];
    const float* bn3v = (const float*)d_in[25];
    const float* fc1w = (const float*)d_in[26];
    const float* fc1b = (const float*)d_in[27];
    const float* fc2w = (const float*)d_in[28];
    const float* fc2b = (const float*)d_in[29];

    const int n  = in_sizes[0] / IN_DIM;  // 50000
    const int ne = in_sizes[1] / 2;       // 1600000

    // Workspace layout (floats): h[n*64] | feat[n*64] | als[n*4] | ald[n*4] |
    // acc[n*64] | denom[n*4] | menc[n*4]   (acc..menc zeroed per layer in one memset)
    float* ws    = (float*)d_ws;
    float*    h     = ws;
    float*    feat  = h + (size_t)n * 64;
    float*    als   = feat + (size_t)n * 64;
    float*    ald   = als + (size_t)n * 4;
    float*    acc   = ald + (size_t)n * 4;
    float*    denom = acc + (size_t)n * 64;
    unsigned* menc  = (unsigned*)(denom + (size_t)n * 4);

    auto cdiv = [](long a, long b) { return (int)((a + b - 1) / b); };
    const size_t zero_bytes = (size_t)n * 72 * sizeof(float);  // acc + denom + menc

    // ---------------- Layer 1: F=128 -> H=4, C=16 ----------------
    hipMemsetAsync(acc, 0, zero_bytes, stream);
    gemm_kernel<128, 64><<<cdiv(n, 4), 256, 0, stream>>>(x, W1, h, n);
    al_kernel<4, 16><<<cdiv((long)n * 4, 256), 256, 0, stream>>>(h, As1, Ad1, als, ald, n);
    edge_max_kernel<4><<<cdiv((long)ne + n, 256), 256, 0, stream>>>(ei, als, ald, menc, ne, n);
    edge_acc_kernel<4, 16><<<cdiv(((long)ne + n) * 4, 256), 256, 0, stream>>>(
        ei, als, ald, menc, h, denom, acc, ne, n);
    finalize_kernel<4, 16><<<cdiv((long)n * 64, 256), 256, 0, stream>>>(
        acc, denom, b1, bn1g, bn1b, bn1m, bn1v, feat, n);

    // ---------------- Layer 2: F=64 -> H=4, C=16 ----------------
    hipMemsetAsync(acc, 0, zero_bytes, stream);
    gemm_kernel<64, 64><<<cdiv(n, 4), 256, 0, stream>>>(feat, W2, h, n);
    al_kernel<4, 16><<<cdiv((long)n * 4, 256), 256, 0, stream>>>(h, As2, Ad2, als, ald, n);
    edge_max_kernel<4><<<cdiv((long)ne + n, 256), 256, 0, stream>>>(ei, als, ald, menc, ne, n);
    edge_acc_kernel<4, 16><<<cdiv(((long)ne + n) * 4, 256), 256, 0, stream>>>(
        ei, als, ald, menc, h, denom, acc, ne, n);
    finalize_kernel<4, 16><<<cdiv((long)n * 64, 256), 256, 0, stream>>>(
        acc, denom, b2, bn2g, bn2b, bn2m, bn2v, feat, n);

    // ---------------- Layer 3: F=64 -> H=1, C=16 ----------------
    hipMemsetAsync(acc, 0, zero_bytes, stream);
    gemm_kernel<64, 16><<<cdiv(n, 16), 256, 0, stream>>>(feat, W3, h, n);
    al_kernel<1, 16><<<cdiv((long)n, 256), 256, 0, stream>>>(h, As3, Ad3, als, ald, n);
    edge_max_kernel<1><<<cdiv((long)ne + n, 256), 256, 0, stream>>>(ei, als, ald, menc, ne, n);
    edge_acc_kernel<1, 16><<<cdiv((long)ne + n, 256), 256, 0, stream>>>(
        ei, als, ald, menc, h, denom, acc, ne, n);
    finalize_kernel<1, 16><<<cdiv((long)n * 16, 256), 256, 0, stream>>>(
        acc, denom, b3, bn3g, bn3b, bn3m, bn3v, feat, n);

    // ---------------- MLP head ----------------
    mlp_kernel<<<cdiv(n, 256), 256, 0, stream>>>(feat, fc1w, fc1b, fc2w, fc2b,
                                                 (float*)d_out, n);
}

// Round 2
// 874.907 us; speedup vs baseline: 16.6133x; 16.6133x over previous
//
#include <hip/hip_runtime.h>

#define IN_DIM 128

__device__ __forceinline__ float lrelu(float x) { return x > 0.f ? x : 0.2f * x; }

// ---------------- dense node GEMM: h[n,HC] = in[n,F] @ W[F,HC] ----------------
template<int F, int HC>
__global__ __launch_bounds__(256) void gemm_kernel(const float* __restrict__ in,
                                                   const float* __restrict__ W,
                                                   float* __restrict__ h, int n) {
    constexpr int NPB = 256 / HC;  // nodes per block
    __shared__ float wl[F * HC];
    __shared__ float xl[NPB * F];
    const int t = threadIdx.x;
    for (int i = t; i < F * HC; i += 256) wl[i] = W[i];
    const int node0 = blockIdx.x * NPB;
    for (int i = t; i < NPB * F; i += 256) {
        int node = node0 + i / F;
        xl[i] = (node < n) ? in[node * F + (i % F)] : 0.f;
    }
    __syncthreads();
    const int nl = t / HC, col = t % HC;
    const int node = node0 + nl;
    if (node >= n) return;
    float acc = 0.f;
#pragma unroll
    for (int k = 0; k < F; ++k) acc += xl[nl * F + k] * wl[k * HC + col];
    h[node * HC + col] = acc;
}

// ---------------- per-node attention logits ----------------
template<int H, int C>
__global__ __launch_bounds__(256) void al_kernel(const float* __restrict__ h,
                                                 const float* __restrict__ a_s,
                                                 const float* __restrict__ a_d,
                                                 float* __restrict__ als,
                                                 float* __restrict__ ald, int n) {
    int tid = blockIdx.x * blockDim.x + threadIdx.x;
    if (tid >= n * H) return;
    int node = tid / H, hh = tid % H;
    const float* hp = h + (node * H + hh) * C;
    const float* as = a_s + hh * C;
    const float* ad = a_d + hh * C;
    float s = 0.f, d0 = 0.f;
#pragma unroll
    for (int c = 0; c < C; ++c) {
        float v = hp[c];
        s += v * as[c];
        d0 += v * ad[c];
    }
    als[tid] = s;
    ald[tid] = d0;
}

// ---------------- CSR build (counting sort by dst) ----------------
__global__ __launch_bounds__(256) void deg_kernel(const int* __restrict__ ei,
                                                  int* __restrict__ deg, int ne, int n) {
    int e = blockIdx.x * 256 + threadIdx.x;
    if (e >= ne + n) return;
    int d = (e < ne) ? ei[ne + e] : (e - ne);
    atomicAdd(deg + d, 1);
}

// Single-block exclusive scan over deg[0..n) -> off[0..n], cursor copy.
__global__ __launch_bounds__(1024) void scan_kernel(const int* __restrict__ deg,
                                                    int* __restrict__ off,
                                                    int* __restrict__ cursor, int n) {
    __shared__ int sums[1024];
    int t = threadIdx.x;
    int items = (n + 1023) / 1024;
    int begin = t * items;
    int endi = min(begin + items, n);
    int s = 0;
    for (int i = begin; i < endi; ++i) s += deg[i];
    sums[t] = s;
    __syncthreads();
    int v = s;
    for (int o = 1; o < 1024; o <<= 1) {
        int other = (t >= o) ? sums[t - o] : 0;
        __syncthreads();
        v += other;
        sums[t] = v;
        __syncthreads();
    }
    int run = v - s;  // exclusive base
    for (int i = begin; i < endi; ++i) {
        off[i] = run;
        cursor[i] = run;
        run += deg[i];
    }
    if (t == 1023) off[n] = run;
}

__global__ __launch_bounds__(256) void scatter_kernel(const int* __restrict__ ei,
                                                      int* __restrict__ cursor,
                                                      int* __restrict__ csr, int ne, int n) {
    int e = blockIdx.x * 256 + threadIdx.x;
    if (e >= ne + n) return;
    int s, d;
    if (e < ne) { s = ei[e]; d = ei[ne + e]; } else { s = d = e - ne; }
    int pos = atomicAdd(cursor + d, 1);
    csr[pos] = s;
}

// ---------------- aggregation: one wave per dst node, online softmax ----------
// H*C == 64: lane = head*16 + channel; all state lane-local. BN/ReLU fused.
template<int H, int C>
__global__ __launch_bounds__(256) void agg64_kernel(const int* __restrict__ off,
                                                    const int* __restrict__ csr,
                                                    const float* __restrict__ als,
                                                    const float* __restrict__ ald,
                                                    const float* __restrict__ h,
                                                    const float* __restrict__ bias,
                                                    const float* __restrict__ g,
                                                    const float* __restrict__ bb,
                                                    const float* __restrict__ mm,
                                                    const float* __restrict__ vv,
                                                    float* __restrict__ feat, int n) {
    int wave = (blockIdx.x * blockDim.x + threadIdx.x) >> 6;
    int lane = threadIdx.x & 63;
    if (wave >= n) return;
    int head = lane / C;
    int start = off[wave], end = off[wave + 1];
    float aldv = ald[wave * H + head];
    float m = -1e30f, l = 0.f, acc = 0.f;
    for (int i = start; i < end; ++i) {
        int s = csr[i];
        float e = lrelu(als[s * H + head] + aldv);
        float hv = h[(size_t)s * 64 + lane];
        float mn = fmaxf(m, e);
        float sc = __expf(m - mn);   // first iter: exp(-1e30) == 0
        float w = __expf(e - mn);
        acc = acc * sc + w * hv;
        l = l * sc + w;
        m = mn;
    }
    float val = acc / (l + 1e-16f) + bias[lane];
    val = (val - mm[lane]) * rsqrtf(vv[lane] + 1e-5f) * g[lane] + bb[lane];
    feat[(size_t)wave * 64 + lane] = fmaxf(val, 0.f);
}

// H=1, C=16: 4 edge-groups of 16 lanes each, merged by shfl_xor at the end.
__global__ __launch_bounds__(256) void agg16_kernel(const int* __restrict__ off,
                                                    const int* __restrict__ csr,
                                                    const float* __restrict__ als,
                                                    const float* __restrict__ ald,
                                                    const float* __restrict__ h,
                                                    const float* __restrict__ bias,
                                                    const float* __restrict__ g,
                                                    const float* __restrict__ bb,
                                                    const float* __restrict__ mm,
                                                    const float* __restrict__ vv,
                                                    float* __restrict__ feat, int n) {
    int wave = (blockIdx.x * blockDim.x + threadIdx.x) >> 6;
    int lane = threadIdx.x & 63;
    if (wave >= n) return;
    int grp = lane >> 4, c = lane & 15;
    int start = off[wave], end = off[wave + 1];
    float aldv = ald[wave];
    float m = -1e30f, l = 0.f, acc = 0.f;
    for (int i = start + grp; i < end; i += 4) {
        int s = csr[i];
        float e = lrelu(als[s] + aldv);
        float hv = h[(size_t)s * 16 + c];
        float mn = fmaxf(m, e);
        float sc = __expf(m - mn);
        float w = __expf(e - mn);
        acc = acc * sc + w * hv;
        l = l * sc + w;
        m = mn;
    }
    // merge the 4 group-partials (m stays >= -1e30, so exponents stay finite)
#pragma unroll
    for (int msk = 16; msk < 64; msk <<= 1) {
        float m2 = __shfl_xor(m, msk, 64);
        float l2 = __shfl_xor(l, msk, 64);
        float a2 = __shfl_xor(acc, msk, 64);
        float mn = fmaxf(m, m2);
        float s1 = __expf(m - mn), s2 = __expf(m2 - mn);
        acc = acc * s1 + a2 * s2;
        l = l * s1 + l2 * s2;
        m = mn;
    }
    if (lane < 16) {
        float val = acc / (l + 1e-16f) + bias[c];
        val = (val - mm[c]) * rsqrtf(vv[c] + 1e-5f) * g[c] + bb[c];
        feat[(size_t)wave * 16 + c] = fmaxf(val, 0.f);
    }
}

// ---------------- per-node MLP head: 16 -> relu(8) -> 1 ----------------
__global__ __launch_bounds__(256) void mlp_kernel(const float* __restrict__ feat,
                                                  const float* __restrict__ w1,
                                                  const float* __restrict__ b1,
                                                  const float* __restrict__ w2,
                                                  const float* __restrict__ b2,
                                                  float* __restrict__ out, int n) {
    int tid = blockIdx.x * blockDim.x + threadIdx.x;
    if (tid >= n) return;
    float f[16];
    const float4* fp = (const float4*)(feat + tid * 16);
#pragma unroll
    for (int i = 0; i < 4; ++i) {
        float4 v = fp[i];
        f[4 * i + 0] = v.x; f[4 * i + 1] = v.y; f[4 * i + 2] = v.z; f[4 * i + 3] = v.w;
    }
    float o = b2[0];
#pragma unroll
    for (int j = 0; j < 8; ++j) {
        float hv = b1[j];
#pragma unroll
        for (int i = 0; i < 16; ++i) hv += f[i] * w1[i * 8 + j];
        hv = fmaxf(hv, 0.f);
        o += hv * w2[j];
    }
    out[tid] = o;
}

extern "C" void kernel_launch(void* const* d_in, const int* in_sizes, int n_in,
                              void* d_out, int out_size, void* d_ws, size_t ws_size,
                              hipStream_t stream) {
    const float* x    = (const float*)d_in[0];
    const int*   ei   = (const int*)d_in[1];
    const float* W1   = (const float*)d_in[2];
    const float* As1  = (const float*)d_in[3];
    const float* Ad1  = (const float*)d_in[4];
    const float* b1   = (const float*)d_in[5];
    const float* bn1g = (const float*)d_in[6];
    const float* bn1b = (const float*)d_in[7];
    const float* bn1m = (const float*)d_in[8];
    const float* bn1v = (const float*)d_in[9];
    const float* W2   = (const float*)d_in[10];
    const float* As2  = (const float*)d_in[11];
    const float* Ad2  = (const float*)d_in[12];
    const float* b2   = (const float*)d_in[13];
    const float* bn2g = (const float*)d_in[14];
    const float* bn2b = (const float*)d_in[15];
    const float* bn2m = (const float*)d_in[16];
    const float* bn2v = (const float*)d_in[17];
    const float* W3   = (const float*)d_in[18];
    const float* As3  = (const float*)d_in[19];
    const float* Ad3  = (const float*)d_in[20];
    const float* b3   = (const float*)d_in[21];
    const float* bn3g = (const float*)d_in[22];
    const float* bn3b = (const float*)d_in[23];
    const float* bn3m = (const float*)d_in[24];
    const float* bn3v = (const float*)d_in[25];
    const float* fc1w = (const float*)d_in[26];
    const float* fc1b = (const float*)d_in[27];
    const float* fc2w = (const float*)d_in[28];
    const float* fc2b = (const float*)d_in[29];

    const int n  = in_sizes[0] / IN_DIM;  // 50000
    const int ne = in_sizes[1] / 2;       // 1600000
    const int et = ne + n;                // edges incl. self-loops

    // Workspace layout:
    // floats: h[n*64] | feat[n*64] | als[n*4] | ald[n*4]
    // ints:   deg[n] | off[n+1] | cursor[n] | csr[et]
    float* h    = (float*)d_ws;
    float* feat = h + (size_t)n * 64;
    float* als  = feat + (size_t)n * 64;
    float* ald  = als + (size_t)n * 4;
    int* deg    = (int*)(ald + (size_t)n * 4);
    int* off    = deg + n;
    int* cursor = off + (n + 1);
    int* csr    = cursor + n;

    auto cdiv = [](long a, long b) { return (int)((a + b - 1) / b); };

    // ---- CSR build (per call; graph is identical across calls) ----
    hipMemsetAsync(deg, 0, (size_t)n * sizeof(int), stream);
    deg_kernel<<<cdiv(et, 256), 256, 0, stream>>>(ei, deg, ne, n);
    scan_kernel<<<1, 1024, 0, stream>>>(deg, off, cursor, n);
    scatter_kernel<<<cdiv(et, 256), 256, 0, stream>>>(ei, cursor, csr, ne, n);

    // ---- Layer 1: F=128 -> H=4,C=16 ----
    gemm_kernel<128, 64><<<cdiv(n, 4), 256, 0, stream>>>(x, W1, h, n);
    al_kernel<4, 16><<<cdiv((long)n * 4, 256), 256, 0, stream>>>(h, As1, Ad1, als, ald, n);
    agg64_kernel<4, 16><<<cdiv(n, 4), 256, 0, stream>>>(off, csr, als, ald, h,
        b1, bn1g, bn1b, bn1m, bn1v, feat, n);

    // ---- Layer 2: F=64 -> H=4,C=16 ----
    gemm_kernel<64, 64><<<cdiv(n, 4), 256, 0, stream>>>(feat, W2, h, n);
    al_kernel<4, 16><<<cdiv((long)n * 4, 256), 256, 0, stream>>>(h, As2, Ad2, als, ald, n);
    agg64_kernel<4, 16><<<cdiv(n, 4), 256, 0, stream>>>(off, csr, als, ald, h,
        b2, bn2g, bn2b, bn2m, bn2v, feat, n);

    // ---- Layer 3: F=64 -> H=1,C=16 ----
    gemm_kernel<64, 16><<<cdiv(n, 16), 256, 0, stream>>>(feat, W3, h, n);
    al_kernel<1, 16><<<cdiv((long)n, 256), 256, 0, stream>>>(h, As3, Ad3, als, ald, n);
    agg16_kernel<<<cdiv(n, 4), 256, 0, stream>>>(off, csr, als, ald, h,
        b3, bn3g, bn3b, bn3m, bn3v, feat, n);

    // ---- MLP head ----
    mlp_kernel<<<cdiv(n, 256), 256, 0, stream>>>(feat, fc1w, fc1b, fc2w, fc2b,
                                                 (float*)d_out, n);
}

// Round 3
// 710.305 us; speedup vs baseline: 20.4631x; 1.2317x over previous
//
#include <hip/hip_runtime.h>

#define IN_DIM 128

__device__ __forceinline__ float lrelu(float x) { return x > 0.f ? x : 0.2f * x; }

// ---- dense node GEMM + fused attention-logit epilogue ----
// h[n,HC] = in[n,F] @ W[F,HC]; als/ald[n,H] = sum_c h*a (C=16 lanes shfl-reduce)
template<int F, int HC, int H>
__global__ __launch_bounds__(256) void gemm_al_kernel(const float* __restrict__ in,
                                                      const float* __restrict__ W,
                                                      const float* __restrict__ a_s,
                                                      const float* __restrict__ a_d,
                                                      float* __restrict__ h,
                                                      float* __restrict__ als,
                                                      float* __restrict__ ald, int n) {
    constexpr int NPB = 256 / HC;  // nodes per block (n divisible by NPB for our sizes)
    __shared__ float wl[F * HC];
    __shared__ float xl[NPB * F];
    const int t = threadIdx.x;
    for (int i = t; i < F * HC; i += 256) wl[i] = W[i];
    const int node0 = blockIdx.x * NPB;
    for (int i = t; i < NPB * F; i += 256) {
        int node = node0 + i / F;
        xl[i] = (node < n) ? in[node * F + (i % F)] : 0.f;
    }
    __syncthreads();
    const int nl = t / HC, col = t % HC;
    const int node = node0 + nl;
    if (node >= n) return;
    float acc = 0.f;
#pragma unroll
    for (int k = 0; k < F; ++k) acc += xl[nl * F + k] * wl[k * HC + col];
    h[node * HC + col] = acc;
    // fused logits: reduce over the 16 channels of this head (consecutive lanes)
    float ps = acc * a_s[col];
    float pd = acc * a_d[col];
#pragma unroll
    for (int msk = 1; msk < 16; msk <<= 1) {
        ps += __shfl_xor(ps, msk, 64);
        pd += __shfl_xor(pd, msk, 64);
    }
    if ((col & 15) == 0) {
        int head = col >> 4;
        als[node * H + head] = ps;
        ald[node * H + head] = pd;
    }
}

// ---------------- CSR build (counting sort by dst) ----------------
__global__ __launch_bounds__(256) void deg_kernel(const int* __restrict__ ei,
                                                  int* __restrict__ deg, int ne, int n) {
    int e = blockIdx.x * 256 + threadIdx.x;
    if (e >= ne + n) return;
    int d = (e < ne) ? ei[ne + e] : (e - ne);
    atomicAdd(deg + d, 1);
}

__global__ __launch_bounds__(1024) void scan_kernel(const int* __restrict__ deg,
                                                    int* __restrict__ off,
                                                    int* __restrict__ cursor, int n) {
    __shared__ int sums[1024];
    int t = threadIdx.x;
    int items = (n + 1023) / 1024;
    int begin = t * items;
    int endi = min(begin + items, n);
    int s = 0;
    for (int i = begin; i < endi; ++i) s += deg[i];
    sums[t] = s;
    __syncthreads();
    int v = s;
    for (int o = 1; o < 1024; o <<= 1) {
        int other = (t >= o) ? sums[t - o] : 0;
        __syncthreads();
        v += other;
        sums[t] = v;
        __syncthreads();
    }
    int run = v - s;  // exclusive base
    for (int i = begin; i < endi; ++i) {
        off[i] = run;
        cursor[i] = run;
        run += deg[i];
    }
    if (t == 1023) off[n] = run;
}

__global__ __launch_bounds__(256) void scatter_kernel(const int* __restrict__ ei,
                                                      int* __restrict__ cursor,
                                                      int* __restrict__ csr, int ne, int n) {
    int e = blockIdx.x * 256 + threadIdx.x;
    if (e >= ne + n) return;
    int s, d;
    if (e < ne) { s = ei[e]; d = ei[ne + e]; } else { s = d = e - ne; }
    int pos = atomicAdd(cursor + d, 1);
    csr[pos] = s;
}

// ---- aggregation, H=4 C=16: one wave per dst, two-pass softmax ----
__global__ __launch_bounds__(256) void agg64_kernel(const int* __restrict__ off,
                                                    const int* __restrict__ csr,
                                                    const float* __restrict__ als,
                                                    const float* __restrict__ ald,
                                                    const float* __restrict__ h,
                                                    const float* __restrict__ bias,
                                                    const float* __restrict__ g,
                                                    const float* __restrict__ bb,
                                                    const float* __restrict__ mm,
                                                    const float* __restrict__ vv,
                                                    float* __restrict__ feat, int n) {
    int wave = (blockIdx.x * blockDim.x + threadIdx.x) >> 6;
    int lane = threadIdx.x & 63;
    if (wave >= n) return;
    const int start = off[wave], end = off[wave + 1], deg = end - start;

    // ---- pass A: per-head max, 16 edges/iter across the wave ----
    const int ha = lane & 3;   // head this lane evaluates in pass A
    const int el = lane >> 2;  // edge slot 0..15
    float alda = ald[(wave << 2) + ha];
    float m = -1e30f;
    for (int i = el; i < deg; i += 16) {
        int s = csr[start + i];
        m = fmaxf(m, lrelu(als[(s << 2) + ha] + alda));
    }
#pragma unroll
    for (int msk = 4; msk < 64; msk <<= 1) m = fmaxf(m, __shfl_xor(m, msk, 64));

    // ---- pass B: independent accumulate with fixed max, unroll x8 ----
    const int head = lane >> 4;
    const float mh = __shfl(m, head, 64);  // lanes 0..3 hold head 0..3 maxima
    const float aldv = ald[(wave << 2) + head];
    float l = 0.f, acc = 0.f;
    int i = start;
    const int endb = start + (deg & ~7);
    for (; i < endb; i += 8) {
        int s[8];
#pragma unroll
        for (int j = 0; j < 8; ++j) s[j] = csr[i + j];
        float ev[8], hv[8];
#pragma unroll
        for (int j = 0; j < 8; ++j) ev[j] = als[(s[j] << 2) + head];
#pragma unroll
        for (int j = 0; j < 8; ++j) hv[j] = h[(s[j] << 6) + lane];
#pragma unroll
        for (int j = 0; j < 8; ++j) {
            float w = __expf(lrelu(ev[j] + aldv) - mh);
            l += w;
            acc = fmaf(w, hv[j], acc);
        }
    }
    for (; i < end; ++i) {
        int s = csr[i];
        float w = __expf(lrelu(als[(s << 2) + head] + aldv) - mh);
        l += w;
        acc = fmaf(w, h[(s << 6) + lane], acc);
    }
    float val = acc / (l + 1e-16f) + bias[lane];
    val = (val - mm[lane]) * rsqrtf(vv[lane] + 1e-5f) * g[lane] + bb[lane];
    feat[((size_t)wave << 6) + lane] = fmaxf(val, 0.f);
}

// ---- aggregation, H=1 C=16: 4 edge-groups of 16 lanes, two-pass ----
__global__ __launch_bounds__(256) void agg16_kernel(const int* __restrict__ off,
                                                    const int* __restrict__ csr,
                                                    const float* __restrict__ als,
                                                    const float* __restrict__ ald,
                                                    const float* __restrict__ h,
                                                    const float* __restrict__ bias,
                                                    const float* __restrict__ g,
                                                    const float* __restrict__ bb,
                                                    const float* __restrict__ mm,
                                                    const float* __restrict__ vv,
                                                    float* __restrict__ feat, int n) {
    int wave = (blockIdx.x * blockDim.x + threadIdx.x) >> 6;
    int lane = threadIdx.x & 63;
    if (wave >= n) return;
    const int start = off[wave], end = off[wave + 1], deg = end - start;
    const float aldv = ald[wave];

    // ---- pass A: global max, 64 edges/iter ----
    float m = -1e30f;
    for (int i = lane; i < deg; i += 64) {
        int s = csr[start + i];
        m = fmaxf(m, lrelu(als[s] + aldv));
    }
#pragma unroll
    for (int msk = 1; msk < 64; msk <<= 1) m = fmaxf(m, __shfl_xor(m, msk, 64));

    // ---- pass B: group g handles edges g, g+4, ...; batch x4 ----
    const int grp = lane >> 4, c = lane & 15;
    float l = 0.f, acc = 0.f;
    int nk = (deg - grp + 3) >> 2;  // #edges for this group (deg>=1 always)
    if (deg - grp <= 0) nk = 0;
    int k = 0;
    for (; k + 4 <= nk; k += 4) {
        int base = start + grp + 4 * k;
        int s0 = csr[base], s1 = csr[base + 4], s2 = csr[base + 8], s3 = csr[base + 12];
        float e0 = als[s0], e1 = als[s1], e2 = als[s2], e3 = als[s3];
        float h0 = h[(s0 << 4) + c], h1 = h[(s1 << 4) + c];
        float h2 = h[(s2 << 4) + c], h3 = h[(s3 << 4) + c];
        float w0 = __expf(lrelu(e0 + aldv) - m);
        float w1 = __expf(lrelu(e1 + aldv) - m);
        float w2 = __expf(lrelu(e2 + aldv) - m);
        float w3 = __expf(lrelu(e3 + aldv) - m);
        l += w0 + w1 + w2 + w3;
        acc = fmaf(w0, h0, fmaf(w1, h1, fmaf(w2, h2, fmaf(w3, h3, acc))));
    }
    for (; k < nk; ++k) {
        int s = csr[start + grp + 4 * k];
        float w = __expf(lrelu(als[s] + aldv) - m);
        l += w;
        acc = fmaf(w, h[(s << 4) + c], acc);
    }
    // merge the 4 groups (same m everywhere -> plain sums)
#pragma unroll
    for (int msk = 16; msk < 64; msk <<= 1) {
        l += __shfl_xor(l, msk, 64);
        acc += __shfl_xor(acc, msk, 64);
    }
    if (lane < 16) {
        float val = acc / (l + 1e-16f) + bias[c];
        val = (val - mm[c]) * rsqrtf(vv[c] + 1e-5f) * g[c] + bb[c];
        feat[((size_t)wave << 4) + c] = fmaxf(val, 0.f);
    }
}

// ---------------- per-node MLP head: 16 -> relu(8) -> 1 ----------------
__global__ __launch_bounds__(256) void mlp_kernel(const float* __restrict__ feat,
                                                  const float* __restrict__ w1,
                                                  const float* __restrict__ b1,
                                                  const float* __restrict__ w2,
                                                  const float* __restrict__ b2,
                                                  float* __restrict__ out, int n) {
    int tid = blockIdx.x * blockDim.x + threadIdx.x;
    if (tid >= n) return;
    float f[16];
    const float4* fp = (const float4*)(feat + tid * 16);
#pragma unroll
    for (int i = 0; i < 4; ++i) {
        float4 v = fp[i];
        f[4 * i + 0] = v.x; f[4 * i + 1] = v.y; f[4 * i + 2] = v.z; f[4 * i + 3] = v.w;
    }
    float o = b2[0];
#pragma unroll
    for (int j = 0; j < 8; ++j) {
        float hv = b1[j];
#pragma unroll
        for (int i = 0; i < 16; ++i) hv += f[i] * w1[i * 8 + j];
        hv = fmaxf(hv, 0.f);
        o += hv * w2[j];
    }
    out[tid] = o;
}

extern "C" void kernel_launch(void* const* d_in, const int* in_sizes, int n_in,
                              void* d_out, int out_size, void* d_ws, size_t ws_size,
                              hipStream_t stream) {
    const float* x    = (const float*)d_in[0];
    const int*   ei   = (const int*)d_in[1];
    const float* W1   = (const float*)d_in[2];
    const float* As1  = (const float*)d_in[3];
    const float* Ad1  = (const float*)d_in[4];
    const float* b1   = (const float*)d_in[5];
    const float* bn1g = (const float*)d_in[6];
    const float* bn1b = (const float*)d_in[7];
    const float* bn1m = (const float*)d_in[8];
    const float* bn1v = (const float*)d_in[9];
    const float* W2   = (const float*)d_in[10];
    const float* As2  = (const float*)d_in[11];
    const float* Ad2  = (const float*)d_in[12];
    const float* b2   = (const float*)d_in[13];
    const float* bn2g = (const float*)d_in[14];
    const float* bn2b = (const float*)d_in[15];
    const float* bn2m = (const float*)d_in[16];
    const float* bn2v = (const float*)d_in[17];
    const float* W3   = (const float*)d_in[18];
    const float* As3  = (const float*)d_in[19];
    const float* Ad3  = (const float*)d_in[20];
    const float* b3   = (const float*)d_in[21];
    const float* bn3g = (const float*)d_in[22];
    const float* bn3b = (const float*)d_in[23];
    const float* bn3m = (const float*)d_in[24];
    const float* bn3v = (const float*)d_in[25];
    const float* fc1w = (const float*)d_in[26];
    const float* fc1b = (const float*)d_in[27];
    const float* fc2w = (const float*)d_in[28];
    const float* fc2b = (const float*)d_in[29];

    const int n  = in_sizes[0] / IN_DIM;  // 50000
    const int ne = in_sizes[1] / 2;       // 1600000
    const int et = ne + n;                // edges incl. self-loops

    // Workspace: floats h[n*64] | feat[n*64] | als[n*4] | ald[n*4]
    //            ints   deg[n] | off[n+1] | cursor[n] | csr[et]
    float* h    = (float*)d_ws;
    float* feat = h + (size_t)n * 64;
    float* als  = feat + (size_t)n * 64;
    float* ald  = als + (size_t)n * 4;
    int* deg    = (int*)(ald + (size_t)n * 4);
    int* off    = deg + n;
    int* cursor = off + (n + 1);
    int* csr    = cursor + n;

    auto cdiv = [](long a, long b) { return (int)((a + b - 1) / b); };

    // ---- CSR build ----
    hipMemsetAsync(deg, 0, (size_t)n * sizeof(int), stream);
    deg_kernel<<<cdiv(et, 256), 256, 0, stream>>>(ei, deg, ne, n);
    scan_kernel<<<1, 1024, 0, stream>>>(deg, off, cursor, n);
    scatter_kernel<<<cdiv(et, 256), 256, 0, stream>>>(ei, cursor, csr, ne, n);

    // ---- Layer 1 ----
    gemm_al_kernel<128, 64, 4><<<cdiv(n, 4), 256, 0, stream>>>(x, W1, As1, Ad1, h, als, ald, n);
    agg64_kernel<<<cdiv(n, 4), 256, 0, stream>>>(off, csr, als, ald, h,
        b1, bn1g, bn1b, bn1m, bn1v, feat, n);

    // ---- Layer 2 ----
    gemm_al_kernel<64, 64, 4><<<cdiv(n, 4), 256, 0, stream>>>(feat, W2, As2, Ad2, h, als, ald, n);
    agg64_kernel<<<cdiv(n, 4), 256, 0, stream>>>(off, csr, als, ald, h,
        b2, bn2g, bn2b, bn2m, bn2v, feat, n);

    // ---- Layer 3 ----
    gemm_al_kernel<64, 16, 1><<<cdiv(n, 16), 256, 0, stream>>>(feat, W3, As3, Ad3, h, als, ald, n);
    agg16_kernel<<<cdiv(n, 4), 256, 0, stream>>>(off, csr, als, ald, h,
        b3, bn3g, bn3b, bn3m, bn3v, feat, n);

    // ---- MLP head ----
    mlp_kernel<<<cdiv(n, 256), 256, 0, stream>>>(feat, fc1w, fc1b, fc2w, fc2b,
                                                 (float*)d_out, n);
}